// Round 1
// baseline (530.454 us; speedup 1.0000x reference)
//
#include <hip/hip_runtime.h>
#include <cstdint>
#include <cstddef>

typedef unsigned short u16;
typedef __attribute__((ext_vector_type(8))) __bf16 bf16x8;
typedef __attribute__((ext_vector_type(4))) float f32x4;
typedef __attribute__((ext_vector_type(8))) u16 u16x8;

#define GAS __attribute__((address_space(1)))
#define LAS __attribute__((address_space(3)))

static __device__ __forceinline__ u16 f2bf(float f) {
  uint32_t u = __builtin_bit_cast(uint32_t, f);
  u += 0x7fffu + ((u >> 16) & 1u);
  return (u16)(u >> 16);
}
static __device__ __forceinline__ float bf2f(u16 v) {
  uint32_t u = ((uint32_t)v) << 16;
  return __builtin_bit_cast(float, u);
}
static __device__ __forceinline__ bf16x8 ldf(const u16* p) {
  return __builtin_bit_cast(bf16x8, *reinterpret_cast<const u16x8*>(p));
}
// global -> LDS async, 16B per lane. LDS base must be wave-uniform; HW writes at base + lane*16.
static __device__ __forceinline__ void gld16(const void* g, void* l) {
  __builtin_amdgcn_global_load_lds((GAS unsigned int*)(uintptr_t)g,
                                   (LAS unsigned int*)l, 16, 0, 0);
}

// ---------------- cast fp32 -> bf16 (RNE) ----------------
__global__ __launch_bounds__(256) void castk(const float* __restrict__ s,
                                             u16* __restrict__ d, int n4) {
  int i = blockIdx.x * 256 + threadIdx.x;
  if (i < n4) {
    const float4 v = reinterpret_cast<const float4*>(s)[i];
    ushort4 o;
    o.x = f2bf(v.x); o.y = f2bf(v.y); o.z = f2bf(v.z); o.w = f2bf(v.w);
    reinterpret_cast<ushort4*>(d)[i] = o;
  }
}

// ---------------- GEMM: C[m][n] = sum_k A[m][k] * B[n][k] ----------------
// A [M,K] bf16 row-major, B [N,K] bf16 row-major (i.e. C = A * B^T).
// 128x128 tile, BK=32, 4 waves (2x2), each wave 64x64 via 4x4 16x16x32 MFMA.
__global__ __launch_bounds__(256, 2)
void gemm_bt(const u16* __restrict__ A, const u16* __restrict__ B,
             void* __restrict__ Cp, int M, int N, int K, int out_f32) {
  __shared__ alignas(16) u16 smA[2][128 * 32];
  __shared__ alignas(16) u16 smB[2][128 * 32];
  const int tid  = threadIdx.x;
  const int lane = tid & 63;
  const int w    = tid >> 6;
  const long m0 = (long)blockIdx.y * 128;
  const long n0 = (long)blockIdx.x * 128;
  const int wm = (w >> 1) * 64, wn = (w & 1) * 64;

  f32x4 acc[4][4] = {};

  // staging geometry: 8KB tile = 16 chunks of 512 u16; chunk (j*4+w), lane covers 16B
  const int lin0 = w * 64 + lane;
  const int lin1 = (4 + w) * 64 + lane;
  const int lrow0 = lin0 >> 2, lcol0 = (lin0 & 3) * 8;
  const int lrow1 = lin1 >> 2, lcol1 = (lin1 & 3) * 8;

  auto stage = [&](int buf, int k0) {
    gld16(A + (m0 + lrow0) * K + k0 + lcol0, &smA[buf][(0 * 4 + w) * 512]);
    gld16(B + (n0 + lrow0) * K + k0 + lcol0, &smB[buf][(0 * 4 + w) * 512]);
    gld16(A + (m0 + lrow1) * K + k0 + lcol1, &smA[buf][(1 * 4 + w) * 512]);
    gld16(B + (n0 + lrow1) * K + k0 + lcol1, &smB[buf][(1 * 4 + w) * 512]);
  };
  auto compute = [&](int buf) {
    const u16* As = smA[buf];
    const u16* Bs = smB[buf];
    const int k8 = (lane >> 4) * 8;
    bf16x8 af[4], bfr[4];
#pragma unroll
    for (int t = 0; t < 4; ++t) {
      af[t]  = ldf(As + (wm + t * 16 + (lane & 15)) * 32 + k8);
      bfr[t] = ldf(Bs + (wn + t * 16 + (lane & 15)) * 32 + k8);
    }
#pragma unroll
    for (int i = 0; i < 4; ++i)
#pragma unroll
      for (int j = 0; j < 4; ++j)
        acc[i][j] = __builtin_amdgcn_mfma_f32_16x16x32_bf16(af[i], bfr[j], acc[i][j], 0, 0, 0);
  };

  stage(0, 0);
  __syncthreads();
  const int NT = K >> 5;
  for (int t = 0; t < NT; ++t) {
    if (t + 1 < NT) stage((t + 1) & 1, (t + 1) << 5);
    compute(t & 1);
    __syncthreads();   // drains vmcnt (stage done) + all waves done reading cur buf
  }

#pragma unroll
  for (int i = 0; i < 4; ++i)
#pragma unroll
    for (int j = 0; j < 4; ++j)
#pragma unroll
      for (int r = 0; r < 4; ++r) {
        long row = m0 + wm + i * 16 + (lane >> 4) * 4 + r;
        long col = n0 + wn + j * 16 + (lane & 15);
        if (out_f32) ((float*)Cp)[row * N + col] = acc[i][j][r];
        else         ((u16*)Cp)[row * N + col]   = f2bf(acc[i][j][r]);
      }
}

// ---------------- RoPE ----------------
// inv_freq[j] = base^(-j/64);  q'[j] = q[j]*c - q[j+64]*s ; q'[j+64] = q[j+64]*c + q[j]*s
// rope_q: in place, folds softmax scale 1/sqrt(128) into Q.
__global__ __launch_bounds__(256) void rope_q(u16* __restrict__ Q) {
  const int m = blockIdx.x;
  const int pos = m & 2047;
  const int t = threadIdx.x;
  const int j = t & 63;
  const float invf = exp2f(-(float)j * 0.20762050593046014f); // log2(10000)/64
  float sn, cs;
  sincosf((float)pos * invf, &sn, &cs);
  const float sc = 0.08838834764831845f; // 1/sqrt(128)
#pragma unroll
  for (int h = t >> 6; h < 16; h += 4) {
    u16* p = Q + (size_t)m * 2048 + h * 128;
    float a = bf2f(p[j]), b = bf2f(p[j + 64]);
    p[j]      = f2bf((a * cs - b * sn) * sc);
    p[j + 64] = f2bf((b * cs + a * sn) * sc);
  }
}

// rope_k: reads K [m][2048], writes blocked+swizzled layout:
// Kb[bh][kb][key*128 + (d ^ ((key&7)<<3))], tile = 64 keys x 128 d (16KB)
__global__ __launch_bounds__(256) void rope_k(const u16* __restrict__ Kt, u16* __restrict__ Kb) {
  const int m = blockIdx.x;
  const int pos = m & 2047;
  const int bb = m >> 11;
  const int kb = pos >> 6;
  const int key = pos & 63;
  const int t = threadIdx.x;
  const int j = t & 63;
  const float invf = exp2f(-(float)j * 0.20762050593046014f);
  float sn, cs;
  sincosf((float)pos * invf, &sn, &cs);
  const int sw = (key & 7) << 3;
#pragma unroll
  for (int h = t >> 6; h < 16; h += 4) {
    const u16* p = Kt + (size_t)m * 2048 + h * 128;
    float a = bf2f(p[j]), b = bf2f(p[j + 64]);
    u16* dst = Kb + ((size_t)(bb * 16 + h) * 32 + kb) * 8192 + key * 128;
    dst[j ^ sw]        = f2bf(a * cs - b * sn);
    dst[(j + 64) ^ sw] = f2bf(b * cs + a * sn);
  }
}

// ---------------- V transpose to blocked [d][key] swizzled ----------------
// Vb[bh][kb][d*64 + (key ^ ((d&7)<<3))]
__global__ __launch_bounds__(256) void transpose_v(const u16* __restrict__ Vt, u16* __restrict__ Vb) {
  __shared__ u16 sm[64][130];
  const int kb = blockIdx.x, bh = blockIdx.y;
  const int bb = bh >> 4, h = bh & 15;
  const int t = threadIdx.x;
#pragma unroll
  for (int r = 0; r < 4; ++r) {
    int c = r * 256 + t;               // 0..1023 chunks of 8 d
    int key = c >> 4, d0 = (c & 15) * 8;
    const u16* src = Vt + (size_t)(bb * 2048 + kb * 64 + key) * 2048 + h * 128 + d0;
    u16x8 v = *reinterpret_cast<const u16x8*>(src);
#pragma unroll
    for (int i = 0; i < 8; ++i) sm[key][d0 + i] = v[i];
  }
  __syncthreads();
  u16* dst = Vb + ((size_t)bh * 32 + kb) * 8192;
#pragma unroll
  for (int r = 0; r < 4; ++r) {
    int c = r * 256 + t;
    int key0 = (c & 7) * 8, d = c >> 3;
    u16x8 v;
#pragma unroll
    for (int i = 0; i < 8; ++i) v[i] = sm[key0 + i][d];
    *reinterpret_cast<u16x8*>(dst + d * 64 + (key0 ^ ((d & 7) << 3))) = v;
  }
}

// ---------------- flash attention ----------------
// grid 1024 blocks: 4 waves/block, 64 q rows/block, KVBLK=64, full (non-causal) softmax.
__global__ __launch_bounds__(256, 2)
void flash_attn(const u16* __restrict__ Q, const u16* __restrict__ Kb,
                const u16* __restrict__ Vb, u16* __restrict__ O) {
  __shared__ alignas(16) u16 smK[64 * 128];
  __shared__ alignas(16) u16 smV[128 * 64];
  __shared__ alignas(16) u16 smP[4][16 * 64];

  const int f = blockIdx.x;
  const int bh = (f & 7) * 4 + (f >> 8);   // XCD-grouping: 4 bh per XCD slot
  const int qb = (f >> 3) & 31;
  const int bb = bh >> 4, h = bh & 15;
  const int lane = threadIdx.x & 63, w = threadIdx.x >> 6;

  // Q fragments (rope'd + pre-scaled), rows qb*64 + w*16 + (lane&15)
  const int qrow = bb * 2048 + qb * 64 + w * 16 + (lane & 15);
  const u16* qp = Q + (size_t)qrow * 2048 + h * 128 + ((lane >> 4) * 8);
  bf16x8 qf[4];
#pragma unroll
  for (int kk = 0; kk < 4; ++kk) qf[kk] = ldf(qp + kk * 32);

  f32x4 oacc[8] = {};
  float mr[4] = {-__builtin_inff(), -__builtin_inff(), -__builtin_inff(), -__builtin_inff()};
  float lr[4] = {0.f, 0.f, 0.f, 0.f};

  const u16* kbase = Kb + (size_t)bh * 32 * 8192;
  const u16* vbase = Vb + (size_t)bh * 32 * 8192;

  for (int kb = 0; kb < 32; ++kb) {
    __syncthreads();   // all waves done reading previous K/V tiles
#pragma unroll
    for (int j = 0; j < 4; ++j) {
      int off = (j * 4 + w) * 512;     // u16 units, 1KB chunks
      gld16(kbase + (size_t)kb * 8192 + off + lane * 8, &smK[off]);
      gld16(vbase + (size_t)kb * 8192 + off + lane * 8, &smV[off]);
    }
    __syncthreads();   // staging complete (implicit vmcnt drain)

    // scores: S[q][key] = sum_d Q[q][d] K[key][d]
    f32x4 sacc[4] = {};
#pragma unroll
    for (int nt = 0; nt < 4; ++nt) {
      const int key = nt * 16 + (lane & 15);
      const int sw = (key & 7) << 3;
#pragma unroll
      for (int kk = 0; kk < 4; ++kk) {
        const int d = kk * 32 + (lane >> 4) * 8;
        bf16x8 kf = ldf(&smK[key * 128 + (d ^ sw)]);
        sacc[nt] = __builtin_amdgcn_mfma_f32_16x16x32_bf16(qf[kk], kf, sacc[nt], 0, 0, 0);
      }
    }

    // online softmax (rows = (lane>>4)*4 + r, reduce over 16 lanes of lane&15)
    float nm[4], fac[4];
#pragma unroll
    for (int r = 0; r < 4; ++r) {
      float mx = fmaxf(fmaxf(sacc[0][r], sacc[1][r]), fmaxf(sacc[2][r], sacc[3][r]));
#pragma unroll
      for (int o = 1; o < 16; o <<= 1) mx = fmaxf(mx, __shfl_xor(mx, o));
      nm[r] = fmaxf(mr[r], mx);
      fac[r] = exp2f((mr[r] - nm[r]) * 1.4426950408889634f);
      mr[r] = nm[r];
    }
#pragma unroll
    for (int nt = 0; nt < 4; ++nt)
#pragma unroll
      for (int r = 0; r < 4; ++r)
        sacc[nt][r] = exp2f((sacc[nt][r] - nm[r]) * 1.4426950408889634f);
#pragma unroll
    for (int r = 0; r < 4; ++r) {
      float s = (sacc[0][r] + sacc[1][r]) + (sacc[2][r] + sacc[3][r]);
#pragma unroll
      for (int o = 1; o < 16; o <<= 1) s += __shfl_xor(s, o);
      lr[r] = lr[r] * fac[r] + s;
    }
#pragma unroll
    for (int t = 0; t < 8; ++t)
#pragma unroll
      for (int r = 0; r < 4; ++r) oacc[t][r] *= fac[r];

    // P -> LDS (bf16, swizzled rows)
    u16* pw = smP[w];
#pragma unroll
    for (int r = 0; r < 4; ++r) {
      const int row = (lane >> 4) * 4 + r;
      const int sw = (row & 7) << 3;
#pragma unroll
      for (int nt = 0; nt < 4; ++nt) {
        const int col = nt * 16 + (lane & 15);
        pw[row * 64 + (col ^ sw)] = f2bf(sacc[nt][r]);
      }
    }

    // PV: O[q][d] += sum_key P[q][key] V[key][d]
#pragma unroll
    for (int kk2 = 0; kk2 < 2; ++kk2) {
      const int k0 = kk2 * 32 + (lane >> 4) * 8;
      const int prow = lane & 15;
      bf16x8 pf = ldf(&pw[prow * 64 + (k0 ^ ((prow & 7) << 3))]);
#pragma unroll
      for (int t = 0; t < 8; ++t) {
        const int d = t * 16 + (lane & 15);
        bf16x8 vf = ldf(&smV[d * 64 + (k0 ^ ((d & 7) << 3))]);
        oacc[t] = __builtin_amdgcn_mfma_f32_16x16x32_bf16(pf, vf, oacc[t], 0, 0, 0);
      }
    }
  }

  // epilogue: normalize and store bf16 at [m][h*128+d]
#pragma unroll
  for (int r = 0; r < 4; ++r) lr[r] = 1.0f / lr[r];
  const int orow0 = bb * 2048 + qb * 64 + w * 16;
#pragma unroll
  for (int t = 0; t < 8; ++t)
#pragma unroll
    for (int r = 0; r < 4; ++r) {
      const int row = orow0 + (lane >> 4) * 4 + r;
      const int d = t * 16 + (lane & 15);
      O[(size_t)row * 2048 + h * 128 + d] = f2bf(oacc[t][r] * lr[r]);
    }
}

// ---------------- host ----------------
extern "C" void kernel_launch(void* const* d_in, const int* in_sizes, int n_in,
                              void* d_out, int out_size, void* d_ws, size_t ws_size,
                              hipStream_t stream) {
  const float* X  = (const float*)d_in[0];
  const float* Wq = (const float*)d_in[1];
  const float* Wk = (const float*)d_in[2];
  const float* Wv = (const float*)d_in[3];
  const float* Wo = (const float*)d_in[4];
  float* out = (float*)d_out;
  char* ws = (char*)d_ws;
  const size_t MB = 1u << 20;
  u16* Xb   = (u16*)(ws + 0   * MB);   // 16MB, reused as Kblk after QKV GEMMs
  u16* Qb   = (u16*)(ws + 16  * MB);
  u16* Ktmp = (u16*)(ws + 32  * MB);   // reused as attn-out after rope_k
  u16* Vtmp = (u16*)(ws + 48  * MB);
  u16* Vblk = (u16*)(ws + 64  * MB);
  u16* Wqb  = (u16*)(ws + 80  * MB);
  u16* Wkb  = (u16*)(ws + 88  * MB);
  u16* Wvb  = (u16*)(ws + 96  * MB);
  u16* Wob  = (u16*)(ws + 104 * MB);
  u16* Kblk = Xb;
  u16* Ob   = Ktmp;

  castk<<<8192, 256, 0, stream>>>(X,  Xb,  2097152);
  castk<<<4096, 256, 0, stream>>>(Wq, Wqb, 1048576);
  castk<<<4096, 256, 0, stream>>>(Wk, Wkb, 1048576);
  castk<<<4096, 256, 0, stream>>>(Wv, Wvb, 1048576);
  castk<<<4096, 256, 0, stream>>>(Wo, Wob, 1048576);

  gemm_bt<<<dim3(16, 32), 256, 0, stream>>>(Xb, Wqb, Qb,   4096, 2048, 2048, 0);
  gemm_bt<<<dim3(16, 32), 256, 0, stream>>>(Xb, Wkb, Ktmp, 4096, 2048, 2048, 0);
  gemm_bt<<<dim3(16, 32), 256, 0, stream>>>(Xb, Wvb, Vtmp, 4096, 2048, 2048, 0);

  rope_q<<<4096, 256, 0, stream>>>(Qb);
  rope_k<<<4096, 256, 0, stream>>>(Ktmp, Kblk);
  transpose_v<<<dim3(32, 32), 256, 0, stream>>>(Vtmp, Vblk);

  flash_attn<<<1024, 256, 0, stream>>>(Qb, Kblk, Vblk, Ob);

  gemm_bt<<<dim3(16, 32), 256, 0, stream>>>(Ob, Wob, out, 4096, 2048, 2048, 1);
}

// Round 6
// 499.662 us; speedup vs baseline: 1.0616x; 1.0616x over previous
//
#include <hip/hip_runtime.h>
#include <cstdint>
#include <cstddef>

typedef unsigned short u16;
typedef __attribute__((ext_vector_type(8))) __bf16 bf16x8;
typedef __attribute__((ext_vector_type(4))) float f32x4;
typedef __attribute__((ext_vector_type(8))) u16 u16x8;

#define GAS __attribute__((address_space(1)))
#define LAS __attribute__((address_space(3)))

static __device__ __forceinline__ u16 f2bf(float f) {
  uint32_t u = __builtin_bit_cast(uint32_t, f);
  u += 0x7fffu + ((u >> 16) & 1u);
  return (u16)(u >> 16);
}
static __device__ __forceinline__ float bf2f(u16 v) {
  uint32_t u = ((uint32_t)v) << 16;
  return __builtin_bit_cast(float, u);
}
static __device__ __forceinline__ bf16x8 ldf(const u16* p) {
  return __builtin_bit_cast(bf16x8, *reinterpret_cast<const u16x8*>(p));
}
static __device__ __forceinline__ void gld16(const void* g, void* l) {
  __builtin_amdgcn_global_load_lds((GAS unsigned int*)(uintptr_t)g,
                                   (LAS unsigned int*)l, 16, 0, 0);
}
#define MFMA __builtin_amdgcn_mfma_f32_16x16x32_bf16

// ---------------- cast fp32 -> bf16 (RNE) ----------------
__global__ __launch_bounds__(256) void castk(const float* __restrict__ s,
                                             u16* __restrict__ d, int n4) {
  int i = blockIdx.x * 256 + threadIdx.x;
  if (i < n4) {
    const float4 v = reinterpret_cast<const float4*>(s)[i];
    ushort4 o;
    o.x = f2bf(v.x); o.y = f2bf(v.y); o.z = f2bf(v.z); o.w = f2bf(v.w);
    reinterpret_cast<ushort4*>(d)[i] = o;
  }
}

// ---------------- 256x256 8-phase GEMM: C = A * B^T ----------------
// A [M,K] bf16 rm, B [N,K] bf16 rm. BK=64 split as two kk-halves of 32.
// LDS: sm[slot(2)][mat A/B (2)][kkhalf(2)] of [256][32] bf16 (16KB each) = 128KB.
// 8 waves (2m x 4n), per-wave 128x64 out = acc[8][4] f32x4.
// Per K-tile: 4 phases {p0:(kk0,nf01) p1:(kk0,nf23) p2:(kk1,nf01) p3:(kk1,nf23)},
// stage order Ah0,Bh0,Ah1,Bh1 (2 gld each); vmcnt(4) at end of p1 and p3.
__global__ __launch_bounds__(512, 2)
void gemm256(const u16* __restrict__ A, const u16* __restrict__ B,
             void* __restrict__ Cp, int M, int N, int K, int out_f32, int nbx) {
  __shared__ alignas(16) u16 sm[8][8192];
  const int tid = threadIdx.x;
  const int lane = tid & 63, w = tid >> 6;
  const int wm = w >> 2, wn = w & 3;
  const int lo = lane & 15, hi8 = (lane >> 4) << 3;

  const int nwg = gridDim.x;
  const int id = blockIdx.x;
  const int idp = (id & 7) * (nwg >> 3) + (id >> 3);   // XCD-contiguous (nwg%8==0)
  const long m0 = (long)(idp / nbx) * 256;
  const long n0 = (long)(idp % nbx) * 256;

  // staging: per gld, wave writes 1KB linear; lds u16 off = g*4096 + w*512 (+lane*8 by HW)
  // -> row = g*128 + w*16 + lane/4, col = (lane&3)*8 within the 32-col half block
  const int srow = w * 16 + (lane >> 2);
  const int scol = (lane & 3) * 8;
  const u16* pA0 = A + (size_t)(m0 + srow) * K + scol;
  const u16* pA1 = A + (size_t)(m0 + 128 + srow) * K + scol;
  const u16* pB0 = B + (size_t)(n0 + srow) * K + scol;
  const u16* pB1 = B + (size_t)(n0 + 128 + srow) * K + scol;
  const int ldso = w * 512;

  auto stA = [&](int slot, int half, int k0) {
    u16* d = sm[(slot << 2) | half];
    gld16(pA0 + k0 + half * 32, d + ldso);
    gld16(pA1 + k0 + half * 32, d + 4096 + ldso);
  };
  auto stB = [&](int slot, int half, int k0) {
    u16* d = sm[(slot << 2) | 2 | half];
    gld16(pB0 + k0 + half * 32, d + ldso);
    gld16(pB1 + k0 + half * 32, d + 4096 + ldso);
  };

  const int aoff = (wm * 128 + lo) * 32 + hi8;
  const int boff = (wn * 64 + lo) * 32 + hi8;

  f32x4 acc[8][4] = {};

  // prologue: stage K-tile 0 fully; need Ah0,Bh0 (oldest 4 gld) before p0
  stA(0, 0, 0); stB(0, 0, 0); stA(0, 1, 0); stB(0, 1, 0);
  asm volatile("s_waitcnt vmcnt(4)" ::: "memory");
  __builtin_amdgcn_s_barrier();

  const int NT = K >> 6;
  for (int kt = 0; kt < NT; ++kt) {
    const int s = kt & 1, so = s ^ 1;
    const int kn = (kt + 1 < NT) ? ((kt + 1) << 6) : 0;  // clamp: stray tile-0 refetch into dead slot
    const u16* sA0 = sm[(s << 2) | 0];
    const u16* sA1 = sm[(s << 2) | 1];
    const u16* sB0 = sm[(s << 2) | 2];
    const u16* sB1 = sm[(s << 2) | 3];

    bf16x8 af[8], b0, b1;
    // ---- p0: kk0, nf 0/1
    b0 = ldf(sB0 + boff);
    b1 = ldf(sB0 + boff + 512);
#pragma unroll
    for (int mf = 0; mf < 8; ++mf) af[mf] = ldf(sA0 + aoff + mf * 512);
    stA(so, 0, kn);
    __builtin_amdgcn_s_barrier();
    asm volatile("s_waitcnt lgkmcnt(0)" ::: "memory");
    __builtin_amdgcn_s_setprio(1);
#pragma unroll
    for (int mf = 0; mf < 8; ++mf) {
      acc[mf][0] = MFMA(af[mf], b0, acc[mf][0], 0, 0, 0);
      acc[mf][1] = MFMA(af[mf], b1, acc[mf][1], 0, 0, 0);
    }
    __builtin_amdgcn_s_setprio(0);
    __builtin_amdgcn_s_barrier();
    // ---- p1: kk0, nf 2/3 (af reused)
    b0 = ldf(sB0 + boff + 1024);
    b1 = ldf(sB0 + boff + 1536);
    stB(so, 0, kn);
    __builtin_amdgcn_s_barrier();
    asm volatile("s_waitcnt lgkmcnt(0)" ::: "memory");
    __builtin_amdgcn_s_setprio(1);
#pragma unroll
    for (int mf = 0; mf < 8; ++mf) {
      acc[mf][2] = MFMA(af[mf], b0, acc[mf][2], 0, 0, 0);
      acc[mf][3] = MFMA(af[mf], b1, acc[mf][3], 0, 0, 0);
    }
    __builtin_amdgcn_s_setprio(0);
    asm volatile("s_waitcnt vmcnt(4)" ::: "memory");   // Ah1,Bh1 of this kt landed
    __builtin_amdgcn_s_barrier();
    // ---- p2: kk1, nf 0/1
    b0 = ldf(sB1 + boff);
    b1 = ldf(sB1 + boff + 512);
#pragma unroll
    for (int mf = 0; mf < 8; ++mf) af[mf] = ldf(sA1 + aoff + mf * 512);
    stA(so, 1, kn);
    __builtin_amdgcn_s_barrier();
    asm volatile("s_waitcnt lgkmcnt(0)" ::: "memory");
    __builtin_amdgcn_s_setprio(1);
#pragma unroll
    for (int mf = 0; mf < 8; ++mf) {
      acc[mf][0] = MFMA(af[mf], b0, acc[mf][0], 0, 0, 0);
      acc[mf][1] = MFMA(af[mf], b1, acc[mf][1], 0, 0, 0);
    }
    __builtin_amdgcn_s_setprio(0);
    __builtin_amdgcn_s_barrier();
    // ---- p3: kk1, nf 2/3
    b0 = ldf(sB1 + boff + 1024);
    b1 = ldf(sB1 + boff + 1536);
    stB(so, 1, kn);
    __builtin_amdgcn_s_barrier();
    asm volatile("s_waitcnt lgkmcnt(0)" ::: "memory");
    __builtin_amdgcn_s_setprio(1);
#pragma unroll
    for (int mf = 0; mf < 8; ++mf) {
      acc[mf][2] = MFMA(af[mf], b0, acc[mf][2], 0, 0, 0);
      acc[mf][3] = MFMA(af[mf], b1, acc[mf][3], 0, 0, 0);
    }
    __builtin_amdgcn_s_setprio(0);
    asm volatile("s_waitcnt vmcnt(4)" ::: "memory");   // Ah0',Bh0' of kt+1 landed
    __builtin_amdgcn_s_barrier();
  }
  asm volatile("s_waitcnt vmcnt(0)" ::: "memory");     // drain stray prefetch before exit

#pragma unroll
  for (int mf = 0; mf < 8; ++mf)
#pragma unroll
    for (int nf = 0; nf < 4; ++nf) {
      const long row = m0 + wm * 128 + mf * 16 + (lane >> 4) * 4;
      const long col = n0 + wn * 64 + nf * 16 + lo;
      if (out_f32) {
        float* C = (float*)Cp;
#pragma unroll
        for (int r = 0; r < 4; ++r) C[(row + r) * N + col] = acc[mf][nf][r];
      } else {
        u16* C = (u16*)Cp;
#pragma unroll
        for (int r = 0; r < 4; ++r) C[(row + r) * N + col] = f2bf(acc[mf][nf][r]);
      }
    }
}

// ---------------- RoPE (QKV fused buffer, row stride 6144) ----------------
__global__ __launch_bounds__(256) void rope_q(u16* __restrict__ QKV) {
  const int m = blockIdx.x;
  const int pos = m & 2047;
  const int t = threadIdx.x;
  const int j = t & 63;
  const float invf = exp2f(-(float)j * 0.20762050593046014f); // log2(10000)/64
  float sn, cs;
  sincosf((float)pos * invf, &sn, &cs);
  const float sc = 0.08838834764831845f; // 1/sqrt(128)
#pragma unroll
  for (int h = t >> 6; h < 16; h += 4) {
    u16* p = QKV + (size_t)m * 6144 + h * 128;
    float a = bf2f(p[j]), b = bf2f(p[j + 64]);
    p[j]      = f2bf((a * cs - b * sn) * sc);
    p[j + 64] = f2bf((b * cs + a * sn) * sc);
  }
}

// rope_k: K at QKV col offset 2048 -> blocked swizzled Kb[bh][kb][key*128 + (d^((key&7)<<3))]
__global__ __launch_bounds__(256) void rope_k(const u16* __restrict__ QKV, u16* __restrict__ Kb) {
  const int m = blockIdx.x;
  const int pos = m & 2047;
  const int bb = m >> 11;
  const int kb = pos >> 6;
  const int key = pos & 63;
  const int t = threadIdx.x;
  const int j = t & 63;
  const float invf = exp2f(-(float)j * 0.20762050593046014f);
  float sn, cs;
  sincosf((float)pos * invf, &sn, &cs);
  const int sw = (key & 7) << 3;
#pragma unroll
  for (int h = t >> 6; h < 16; h += 4) {
    const u16* p = QKV + (size_t)m * 6144 + 2048 + h * 128;
    float a = bf2f(p[j]), b = bf2f(p[j + 64]);
    u16* dst = Kb + ((size_t)(bb * 16 + h) * 32 + kb) * 8192 + key * 128;
    dst[j ^ sw]        = f2bf(a * cs - b * sn);
    dst[(j + 64) ^ sw] = f2bf(b * cs + a * sn);
  }
}

// V (QKV col offset 4096) -> blocked [d][key] swizzled: Vb[bh][kb][d*64 + (key^((d&7)<<3))]
__global__ __launch_bounds__(256) void transpose_v(const u16* __restrict__ QKV, u16* __restrict__ Vb) {
  __shared__ u16 smv[64][130];
  const int kb = blockIdx.x, bh = blockIdx.y;
  const int bb = bh >> 4, h = bh & 15;
  const int t = threadIdx.x;
#pragma unroll
  for (int r = 0; r < 4; ++r) {
    int c = r * 256 + t;
    int key = c >> 4, d0 = (c & 15) * 8;
    const u16* src = QKV + (size_t)(bb * 2048 + kb * 64 + key) * 6144 + 4096 + h * 128 + d0;
    u16x8 v = *reinterpret_cast<const u16x8*>(src);
#pragma unroll
    for (int i = 0; i < 8; ++i) smv[key][d0 + i] = v[i];
  }
  __syncthreads();
  u16* dst = Vb + ((size_t)bh * 32 + kb) * 8192;
#pragma unroll
  for (int r = 0; r < 4; ++r) {
    int c = r * 256 + t;
    int key0 = (c & 7) * 8, d = c >> 3;
    u16x8 v;
#pragma unroll
    for (int i = 0; i < 8; ++i) v[i] = smv[key0 + i][d];
    *reinterpret_cast<u16x8*>(dst + d * 64 + (key0 ^ ((d & 7) << 3))) = v;
  }
}

// ---------------- flash attention ----------------
__global__ __launch_bounds__(256, 2)
void flash_attn(const u16* __restrict__ Q, const u16* __restrict__ Kb,
                const u16* __restrict__ Vb, u16* __restrict__ O) {
  __shared__ alignas(16) u16 smK[64 * 128];
  __shared__ alignas(16) u16 smV[128 * 64];
  __shared__ alignas(16) u16 smP[4][16 * 64];

  const int f = blockIdx.x;
  const int bh = (f & 7) * 4 + (f >> 8);
  const int qb = (f >> 3) & 31;
  const int bb = bh >> 4, h = bh & 15;
  const int lane = threadIdx.x & 63, w = threadIdx.x >> 6;

  const int qrow = bb * 2048 + qb * 64 + w * 16 + (lane & 15);
  const u16* qp = Q + (size_t)qrow * 6144 + h * 128 + ((lane >> 4) * 8);
  bf16x8 qf[4];
#pragma unroll
  for (int kk = 0; kk < 4; ++kk) qf[kk] = ldf(qp + kk * 32);

  f32x4 oacc[8] = {};
  float mr[4] = {-__builtin_inff(), -__builtin_inff(), -__builtin_inff(), -__builtin_inff()};
  float lr[4] = {0.f, 0.f, 0.f, 0.f};

  const u16* kbase = Kb + (size_t)bh * 32 * 8192;
  const u16* vbase = Vb + (size_t)bh * 32 * 8192;

  for (int kb = 0; kb < 32; ++kb) {
    __syncthreads();
#pragma unroll
    for (int j = 0; j < 4; ++j) {
      int off = (j * 4 + w) * 512;
      gld16(kbase + (size_t)kb * 8192 + off + lane * 8, &smK[off]);
      gld16(vbase + (size_t)kb * 8192 + off + lane * 8, &smV[off]);
    }
    __syncthreads();

    f32x4 sacc[4] = {};
    __builtin_amdgcn_s_setprio(1);
#pragma unroll
    for (int nt = 0; nt < 4; ++nt) {
      const int key = nt * 16 + (lane & 15);
      const int sw = (key & 7) << 3;
#pragma unroll
      for (int kk = 0; kk < 4; ++kk) {
        const int d = kk * 32 + (lane >> 4) * 8;
        bf16x8 kf = ldf(&smK[key * 128 + (d ^ sw)]);
        sacc[nt] = MFMA(qf[kk], kf, sacc[nt], 0, 0, 0);
      }
    }
    __builtin_amdgcn_s_setprio(0);

    float nm[4], fac[4];
#pragma unroll
    for (int r = 0; r < 4; ++r) {
      float mx = fmaxf(fmaxf(sacc[0][r], sacc[1][r]), fmaxf(sacc[2][r], sacc[3][r]));
#pragma unroll
      for (int o = 1; o < 16; o <<= 1) mx = fmaxf(mx, __shfl_xor(mx, o));
      nm[r] = fmaxf(mr[r], mx);
      fac[r] = exp2f((mr[r] - nm[r]) * 1.4426950408889634f);
      mr[r] = nm[r];
    }
#pragma unroll
    for (int nt = 0; nt < 4; ++nt)
#pragma unroll
      for (int r = 0; r < 4; ++r)
        sacc[nt][r] = exp2f((sacc[nt][r] - nm[r]) * 1.4426950408889634f);
#pragma unroll
    for (int r = 0; r < 4; ++r) {
      float s = (sacc[0][r] + sacc[1][r]) + (sacc[2][r] + sacc[3][r]);
#pragma unroll
      for (int o = 1; o < 16; o <<= 1) s += __shfl_xor(s, o);
      lr[r] = lr[r] * fac[r] + s;
    }
#pragma unroll
    for (int t = 0; t < 8; ++t)
#pragma unroll
      for (int r = 0; r < 4; ++r) oacc[t][r] *= fac[r];

    u16* pw = smP[w];
#pragma unroll
    for (int r = 0; r < 4; ++r) {
      const int row = (lane >> 4) * 4 + r;
      const int sw = (row & 7) << 3;
#pragma unroll
      for (int nt = 0; nt < 4; ++nt) {
        const int col = nt * 16 + (lane & 15);
        pw[row * 64 + (col ^ sw)] = f2bf(sacc[nt][r]);
      }
    }

    __builtin_amdgcn_s_setprio(1);
#pragma unroll
    for (int kk2 = 0; kk2 < 2; ++kk2) {
      const int k0 = kk2 * 32 + (lane >> 4) * 8;
      const int prow = lane & 15;
      bf16x8 pf = ldf(&pw[prow * 64 + (k0 ^ ((prow & 7) << 3))]);
#pragma unroll
      for (int t = 0; t < 8; ++t) {
        const int d = t * 16 + (lane & 15);
        bf16x8 vf = ldf(&smV[d * 64 + (k0 ^ ((d & 7) << 3))]);
        oacc[t] = MFMA(pf, vf, oacc[t], 0, 0, 0);
      }
    }
    __builtin_amdgcn_s_setprio(0);
  }

#pragma unroll
  for (int r = 0; r < 4; ++r) lr[r] = 1.0f / lr[r];
  const int orow0 = bb * 2048 + qb * 64 + w * 16;
#pragma unroll
  for (int t = 0; t < 8; ++t)
#pragma unroll
    for (int r = 0; r < 4; ++r) {
      const int row = orow0 + (lane >> 4) * 4 + r;
      const int d = t * 16 + (lane & 15);
      O[(size_t)row * 2048 + h * 128 + d] = f2bf(oacc[t][r] * lr[r]);
    }
}

// ---------------- host ----------------
extern "C" void kernel_launch(void* const* d_in, const int* in_sizes, int n_in,
                              void* d_out, int out_size, void* d_ws, size_t ws_size,
                              hipStream_t stream) {
  const float* X  = (const float*)d_in[0];
  const float* Wq = (const float*)d_in[1];
  const float* Wk = (const float*)d_in[2];
  const float* Wv = (const float*)d_in[3];
  const float* Wo = (const float*)d_in[4];
  float* out = (float*)d_out;
  char* ws = (char*)d_ws;
  const size_t MB = 1u << 20;
  // layout (104MB): [0,16) Xb then Kblk; [16,64) QKVb; [64,88) Wqkvb then
  // Vblk@[64,80) + Ob@[80,96); [96,104) Wob
  u16* Xb    = (u16*)(ws + 0 * MB);
  u16* QKVb  = (u16*)(ws + 16 * MB);
  u16* Wqkvb = (u16*)(ws + 64 * MB);
  u16* Wob   = (u16*)(ws + 96 * MB);
  u16* Kblk  = Xb;
  u16* Vblk  = (u16*)(ws + 64 * MB);
  u16* Ob    = (u16*)(ws + 80 * MB);

  castk<<<8192, 256, 0, stream>>>(X,  Xb, 2097152);
  castk<<<4096, 256, 0, stream>>>(Wq, Wqkvb, 1048576);
  castk<<<4096, 256, 0, stream>>>(Wk, Wqkvb + 4194304, 1048576);
  castk<<<4096, 256, 0, stream>>>(Wv, Wqkvb + 8388608, 1048576);
  castk<<<4096, 256, 0, stream>>>(Wo, Wob, 1048576);

  gemm256<<<384, 512, 0, stream>>>(Xb, Wqkvb, QKVb, 4096, 6144, 2048, 0, 24);

  rope_q<<<4096, 256, 0, stream>>>(QKVb);
  rope_k<<<4096, 256, 0, stream>>>(QKVb, Kblk);
  transpose_v<<<dim3(32, 32), 256, 0, stream>>>(QKVb, Vblk);

  flash_attn<<<1024, 256, 0, stream>>>(QKVb, Kblk, Vblk, Ob);

  gemm256<<<128, 512, 0, stream>>>(Ob, Wob, out, 4096, 2048, 2048, 1, 8);
}

// Round 13
// 493.054 us; speedup vs baseline: 1.0759x; 1.0134x over previous
//
#include <hip/hip_runtime.h>
#include <cstdint>
#include <cstddef>

typedef unsigned short u16;
typedef __attribute__((ext_vector_type(8))) __bf16 bf16x8;
typedef __attribute__((ext_vector_type(4))) float f32x4;
typedef __attribute__((ext_vector_type(16))) float f32x16;
typedef __attribute__((ext_vector_type(8))) u16 u16x8;

#define GAS __attribute__((address_space(1)))
#define LAS __attribute__((address_space(3)))

static __device__ __forceinline__ u16 f2bf(float f) {
  uint32_t u = __builtin_bit_cast(uint32_t, f);
  u += 0x7fffu + ((u >> 16) & 1u);
  return (u16)(u >> 16);
}
static __device__ __forceinline__ float bf2f(u16 v) {
  uint32_t u = ((uint32_t)v) << 16;
  return __builtin_bit_cast(float, u);
}
static __device__ __forceinline__ bf16x8 ldf(const u16* p) {
  return __builtin_bit_cast(bf16x8, *reinterpret_cast<const u16x8*>(p));
}
static __device__ __forceinline__ void gld16(const void* g, void* l) {
  __builtin_amdgcn_global_load_lds((GAS unsigned int*)(uintptr_t)g,
                                   (LAS unsigned int*)l, 16, 0, 0);
}
#define MFMA __builtin_amdgcn_mfma_f32_16x16x32_bf16
#define MFMA32 __builtin_amdgcn_mfma_f32_32x32x16_bf16

// ---------------- cast fp32 -> bf16 (RNE) ----------------
__global__ __launch_bounds__(256) void castk(const float* __restrict__ s,
                                             u16* __restrict__ d, int n4) {
  int i = blockIdx.x * 256 + threadIdx.x;
  if (i < n4) {
    const float4 v = reinterpret_cast<const float4*>(s)[i];
    ushort4 o;
    o.x = f2bf(v.x); o.y = f2bf(v.y); o.z = f2bf(v.z); o.w = f2bf(v.w);
    reinterpret_cast<ushort4*>(d)[i] = o;
  }
}

// ---------------- 256x256 8-phase GEMM: C = A * B^T ---------------- (passed R6)
__global__ __launch_bounds__(512, 2)
void gemm256(const u16* __restrict__ A, const u16* __restrict__ B,
             void* __restrict__ Cp, int M, int N, int K, int out_f32, int nbx) {
  __shared__ alignas(16) u16 sm[8][8192];
  const int tid = threadIdx.x;
  const int lane = tid & 63, w = tid >> 6;
  const int wm = w >> 2, wn = w & 3;
  const int lo = lane & 15, hi8 = (lane >> 4) << 3;

  const int nwg = gridDim.x;
  const int id = blockIdx.x;
  const int idp = (id & 7) * (nwg >> 3) + (id >> 3);   // XCD-contiguous (nwg%8==0)
  const long m0 = (long)(idp / nbx) * 256;
  const long n0 = (long)(idp % nbx) * 256;

  const int srow = w * 16 + (lane >> 2);
  const int scol = (lane & 3) * 8;
  const u16* pA0 = A + (size_t)(m0 + srow) * K + scol;
  const u16* pA1 = A + (size_t)(m0 + 128 + srow) * K + scol;
  const u16* pB0 = B + (size_t)(n0 + srow) * K + scol;
  const u16* pB1 = B + (size_t)(n0 + 128 + srow) * K + scol;
  const int ldso = w * 512;

  auto stA = [&](int slot, int half, int k0) {
    u16* d = sm[(slot << 2) | half];
    gld16(pA0 + k0 + half * 32, d + ldso);
    gld16(pA1 + k0 + half * 32, d + 4096 + ldso);
  };
  auto stB = [&](int slot, int half, int k0) {
    u16* d = sm[(slot << 2) | 2 | half];
    gld16(pB0 + k0 + half * 32, d + ldso);
    gld16(pB1 + k0 + half * 32, d + 4096 + ldso);
  };

  const int aoff = (wm * 128 + lo) * 32 + hi8;
  const int boff = (wn * 64 + lo) * 32 + hi8;

  f32x4 acc[8][4] = {};

  stA(0, 0, 0); stB(0, 0, 0); stA(0, 1, 0); stB(0, 1, 0);
  asm volatile("s_waitcnt vmcnt(4)" ::: "memory");
  __builtin_amdgcn_s_barrier();

  const int NT = K >> 6;
  for (int kt = 0; kt < NT; ++kt) {
    const int s = kt & 1, so = s ^ 1;
    const int kn = (kt + 1 < NT) ? ((kt + 1) << 6) : 0;
    const u16* sA0 = sm[(s << 2) | 0];
    const u16* sA1 = sm[(s << 2) | 1];
    const u16* sB0 = sm[(s << 2) | 2];
    const u16* sB1 = sm[(s << 2) | 3];

    bf16x8 af[8], b0, b1;
    // ---- p0
    b0 = ldf(sB0 + boff);
    b1 = ldf(sB0 + boff + 512);
#pragma unroll
    for (int mf = 0; mf < 8; ++mf) af[mf] = ldf(sA0 + aoff + mf * 512);
    stA(so, 0, kn);
    __builtin_amdgcn_s_barrier();
    asm volatile("s_waitcnt lgkmcnt(0)" ::: "memory");
    __builtin_amdgcn_s_setprio(1);
#pragma unroll
    for (int mf = 0; mf < 8; ++mf) {
      acc[mf][0] = MFMA(af[mf], b0, acc[mf][0], 0, 0, 0);
      acc[mf][1] = MFMA(af[mf], b1, acc[mf][1], 0, 0, 0);
    }
    __builtin_amdgcn_s_setprio(0);
    __builtin_amdgcn_s_barrier();
    // ---- p1
    b0 = ldf(sB0 + boff + 1024);
    b1 = ldf(sB0 + boff + 1536);
    stB(so, 0, kn);
    __builtin_amdgcn_s_barrier();
    asm volatile("s_waitcnt lgkmcnt(0)" ::: "memory");
    __builtin_amdgcn_s_setprio(1);
#pragma unroll
    for (int mf = 0; mf < 8; ++mf) {
      acc[mf][2] = MFMA(af[mf], b0, acc[mf][2], 0, 0, 0);
      acc[mf][3] = MFMA(af[mf], b1, acc[mf][3], 0, 0, 0);
    }
    __builtin_amdgcn_s_setprio(0);
    asm volatile("s_waitcnt vmcnt(4)" ::: "memory");
    __builtin_amdgcn_s_barrier();
    // ---- p2
    b0 = ldf(sB1 + boff);
    b1 = ldf(sB1 + boff + 512);
#pragma unroll
    for (int mf = 0; mf < 8; ++mf) af[mf] = ldf(sA1 + aoff + mf * 512);
    stA(so, 1, kn);
    __builtin_amdgcn_s_barrier();
    asm volatile("s_waitcnt lgkmcnt(0)" ::: "memory");
    __builtin_amdgcn_s_setprio(1);
#pragma unroll
    for (int mf = 0; mf < 8; ++mf) {
      acc[mf][0] = MFMA(af[mf], b0, acc[mf][0], 0, 0, 0);
      acc[mf][1] = MFMA(af[mf], b1, acc[mf][1], 0, 0, 0);
    }
    __builtin_amdgcn_s_setprio(0);
    __builtin_amdgcn_s_barrier();
    // ---- p3
    b0 = ldf(sB1 + boff + 1024);
    b1 = ldf(sB1 + boff + 1536);
    stB(so, 1, kn);
    __builtin_amdgcn_s_barrier();
    asm volatile("s_waitcnt lgkmcnt(0)" ::: "memory");
    __builtin_amdgcn_s_setprio(1);
#pragma unroll
    for (int mf = 0; mf < 8; ++mf) {
      acc[mf][2] = MFMA(af[mf], b0, acc[mf][2], 0, 0, 0);
      acc[mf][3] = MFMA(af[mf], b1, acc[mf][3], 0, 0, 0);
    }
    __builtin_amdgcn_s_setprio(0);
    asm volatile("s_waitcnt vmcnt(4)" ::: "memory");
    __builtin_amdgcn_s_barrier();
  }
  asm volatile("s_waitcnt vmcnt(0)" ::: "memory");

#pragma unroll
  for (int mf = 0; mf < 8; ++mf)
#pragma unroll
    for (int nf = 0; nf < 4; ++nf) {
      const long row = m0 + wm * 128 + mf * 16 + (lane >> 4) * 4;
      const long col = n0 + wn * 64 + nf * 16 + lo;
      if (out_f32) {
        float* C = (float*)Cp;
#pragma unroll
        for (int r = 0; r < 4; ++r) C[(row + r) * N + col] = acc[mf][nf][r];
      } else {
        u16* C = (u16*)Cp;
#pragma unroll
        for (int r = 0; r < 4; ++r) C[(row + r) * N + col] = f2bf(acc[mf][nf][r]);
      }
    }
}

// ---------------- RoPE (QKV fused buffer, row stride 6144) ----------------
// Q scale folds log2(e) so flash3 computes p = exp2(s - m) directly.
__global__ __launch_bounds__(256) void rope_q(u16* __restrict__ QKV) {
  const int m = blockIdx.x;
  const int pos = m & 2047;
  const int t = threadIdx.x;
  const int j = t & 63;
  const float invf = exp2f(-(float)j * 0.20762050593046014f); // log2(10000)/64
  float sn, cs;
  sincosf((float)pos * invf, &sn, &cs);
  const float sc = 0.08838834764831845f * 1.4426950408889634f; // 1/sqrt(128) * log2(e)
#pragma unroll
  for (int h = t >> 6; h < 16; h += 4) {
    u16* p = QKV + (size_t)m * 6144 + h * 128;
    float a = bf2f(p[j]), b = bf2f(p[j + 64]);
    p[j]      = f2bf((a * cs - b * sn) * sc);
    p[j + 64] = f2bf((b * cs + a * sn) * sc);
  }
}

// rope_k: K at QKV col offset 2048 -> blocked swizzled Kb[bh][kb][key*128 + (d^((key&7)<<3))]
__global__ __launch_bounds__(256) void rope_k(const u16* __restrict__ QKV, u16* __restrict__ Kb) {
  const int m = blockIdx.x;
  const int pos = m & 2047;
  const int bb = m >> 11;
  const int kb = pos >> 6;
  const int key = pos & 63;
  const int t = threadIdx.x;
  const int j = t & 63;
  const float invf = exp2f(-(float)j * 0.20762050593046014f);
  float sn, cs;
  sincosf((float)pos * invf, &sn, &cs);
  const int sw = (key & 7) << 3;
#pragma unroll
  for (int h = t >> 6; h < 16; h += 4) {
    const u16* p = QKV + (size_t)m * 6144 + 2048 + h * 128;
    float a = bf2f(p[j]), b = bf2f(p[j + 64]);
    u16* dst = Kb + ((size_t)(bb * 16 + h) * 32 + kb) * 8192 + key * 128;
    dst[j ^ sw]        = f2bf(a * cs - b * sn);
    dst[(j + 64) ^ sw] = f2bf(b * cs + a * sn);
  }
}

// V (QKV col offset 4096) -> blocked [d][key] swizzled: Vb[bh][kb][d*64 + (key^((d&7)<<3))]
__global__ __launch_bounds__(256) void transpose_v(const u16* __restrict__ QKV, u16* __restrict__ Vb) {
  __shared__ u16 smv[64][130];
  const int kb = blockIdx.x, bh = blockIdx.y;
  const int bb = bh >> 4, h = bh & 15;
  const int t = threadIdx.x;
#pragma unroll
  for (int r = 0; r < 4; ++r) {
    int c = r * 256 + t;
    int key = c >> 4, d0 = (c & 15) * 8;
    const u16* src = QKV + (size_t)(bb * 2048 + kb * 64 + key) * 6144 + 4096 + h * 128 + d0;
    u16x8 v = *reinterpret_cast<const u16x8*>(src);
#pragma unroll
    for (int i = 0; i < 8; ++i) smv[key][d0 + i] = v[i];
  }
  __syncthreads();
  u16* dst = Vb + ((size_t)bh * 32 + kb) * 8192;
#pragma unroll
  for (int r = 0; r < 4; ++r) {
    int c = r * 256 + t;
    int key0 = (c & 7) * 8, d = c >> 3;
    u16x8 v;
#pragma unroll
    for (int i = 0; i < 8; ++i) v[i] = smv[key0 + i][d];
    *reinterpret_cast<u16x8*>(dst + d * 64 + (key0 ^ ((d & 7) << 3))) = v;
  }
}

// ---------------- flash attention v3: swapped-QK^T, in-lane softmax, LDS P-bounce ----------------
// 512 blocks (32 bh x 16 qb), 4 warps x 32 q-rows = 128 rows/block. KVBLK=64, single-buffer K/V.
// S^T = mfma32(A=K, B=Q): lane (q5,hi) holds S[q=q5][key=crow(r,hi)(+32)] -> softmax in-lane.
// P -> per-warp LDS [32q][64key] (XOR-swizzled rows) via f2bf pairs; PV A-frags via ds_read_b128.
// No cross-lane asm: only verified primitives (f2bf, gld16, 32x32 MFMA layouts from m74/m101).
__global__ __launch_bounds__(256, 3)
void flash3(const u16* __restrict__ Q, const u16* __restrict__ Kb,
            const u16* __restrict__ Vb, u16* __restrict__ O) {
  __shared__ alignas(16) u16 smK[8192];
  __shared__ alignas(16) u16 smV[8192];
  __shared__ alignas(16) u16 smP[4][2048];

  const int id = blockIdx.x;
  const int bh = id & 31, qb = id >> 5;   // bh%8 spreads XCDs; qb 0..15
  const int bb = bh >> 4, h = bh & 15;
  const int tid = threadIdx.x, lane = tid & 63, w = tid >> 6;
  const int q5 = lane & 31, hi = lane >> 5;

  // Q B-operand frags (pre-scaled by 1/sqrt(128)*log2e): lane n=q5, k-elems d=ds*16+hi*8+j
  const int qrow = bb * 2048 + qb * 128 + w * 32 + q5;
  const u16* qp = Q + (size_t)qrow * 6144 + h * 128 + hi * 8;
  bf16x8 qf[8];
#pragma unroll
  for (int ds = 0; ds < 8; ++ds) qf[ds] = ldf(qp + ds * 16);

  const u16* kbase = Kb + (size_t)bh * 32 * 8192;
  const u16* vbase = Vb + (size_t)bh * 32 * 8192;

  f32x16 oacc[4] = {};                  // dblk 0..3 -> d = dblk*32 + q5
  float mr = -__builtin_inff(), lr = 0.f;

  const int k0row = q5 * 128, k1row = (32 + q5) * 128;
  const int ksw = (q5 & 7) << 3;        // K-tile row swizzle; also reused for P rows
  const int dh = hi * 8;
  u16* pwarp = smP[w];

  for (int kt = 0; kt < 32; ++kt) {
    __syncthreads();                    // all warps done reading previous K/V tile
    const u16* ks = kbase + (size_t)kt * 8192;
    const u16* vs = vbase + (size_t)kt * 8192;
#pragma unroll
    for (int j = 0; j < 4; ++j) {
      const int off = (w * 4 + j) * 512;
      gld16(ks + off + lane * 8, &smK[off]);
      gld16(vs + off + lane * 8, &smV[off]);
    }
    __syncthreads();                    // staging complete (vmcnt drained before barrier)

    // ---- QK^T (swapped): s0 = keys 0..31, s1 = keys 32..63, for q = q5
    f32x16 s0 = {}, s1 = {};
    __builtin_amdgcn_s_setprio(1);
#pragma unroll
    for (int ds = 0; ds < 8; ++ds) {
      const int dd = (ds * 16 + dh) ^ ksw;
      bf16x8 kf0 = ldf(&smK[k0row + dd]);
      bf16x8 kf1 = ldf(&smK[k1row + dd]);
      s0 = MFMA32(kf0, qf[ds], s0, 0, 0, 0);
      s1 = MFMA32(kf1, qf[ds], s1, 0, 0, 0);
    }
    __builtin_amdgcn_s_setprio(0);

    // ---- online softmax in-lane (partner lane^32 holds the complementary 32 keys of same q)
    float v[32];
#pragma unroll
    for (int i = 0; i < 16; ++i) { v[i] = s0[i]; v[16 + i] = s1[i]; }
#pragma unroll
    for (int st = 16; st >= 1; st >>= 1)
#pragma unroll
      for (int i = 0; i < st; ++i) v[i] = fmaxf(v[i], v[i + st]);
    float pm = fmaxf(v[0], __shfl_xor(v[0], 32));

    if (!__all(pm - mr <= 8.0f)) {      // defer-max (T13)
      float nm = fmaxf(mr, pm);
      float fac = exp2f(mr - nm);
      lr *= fac;
#pragma unroll
      for (int db = 0; db < 4; ++db)
#pragma unroll
        for (int i = 0; i < 16; ++i) oacc[db][i] *= fac;
      mr = nm;
    }

#pragma unroll
    for (int i = 0; i < 16; ++i) {
      s0[i] = exp2f(s0[i] - mr);        // scores carry log2e
      s1[i] = exp2f(s1[i] - mr);
    }
#pragma unroll
    for (int i = 0; i < 16; ++i) { v[i] = s0[i]; v[16 + i] = s1[i]; }
#pragma unroll
    for (int st = 16; st >= 1; st >>= 1)
#pragma unroll
      for (int i = 0; i < st; ++i) v[i] += v[i + st];
    lr += v[0] + __shfl_xor(v[0], 32);

    // ---- P -> LDS: reg pair (2i,2i+1) = adjacent keys crow(2i),crow(2i)+1 (C/D map m74/m101)
#pragma unroll
    for (int i = 0; i < 8; ++i) {
      const int r = 2 * i;
      const int key0 = (r & 3) + 8 * (r >> 2) + 4 * hi;           // even
      const uint32_t p0 = (uint32_t)f2bf(s0[r]) | ((uint32_t)f2bf(s0[r + 1]) << 16);
      const uint32_t p1 = (uint32_t)f2bf(s1[r]) | ((uint32_t)f2bf(s1[r + 1]) << 16);
      *reinterpret_cast<uint32_t*>(&pwarp[q5 * 64 + (key0 ^ ksw)]) = p0;
      *reinterpret_cast<uint32_t*>(&pwarp[q5 * 64 + ((key0 + 32) ^ ksw)]) = p1;
    }

    // ---- PV: A-frag = P[q5][16ks+dh .. +7] read back (lgkmcnt orders same-wave RAW)
    bf16x8 pa[4];
#pragma unroll
    for (int ks2 = 0; ks2 < 4; ++ks2)
      pa[ks2] = ldf(&pwarp[q5 * 64 + ((ks2 * 16 + dh) ^ ksw)]);

    __builtin_amdgcn_s_setprio(1);
#pragma unroll
    for (int db = 0; db < 4; ++db) {
      const int d = db * 32 + q5;
      const int vrow = d * 64;
      const int vsw = (d & 7) << 3;
#pragma unroll
      for (int ks2 = 0; ks2 < 4; ++ks2) {
        bf16x8 vf = ldf(&smV[vrow + ((ks2 * 16 + dh) ^ vsw)]);
        oacc[db] = MFMA32(pa[ks2], vf, oacc[db], 0, 0, 0);
      }
    }
    __builtin_amdgcn_s_setprio(0);
  }

  // ---- epilogue: normalize, store bf16
  const float rinv = 1.0f / lr;
  const int qgb = bb * 2048 + qb * 128 + w * 32;
  const int colb = h * 128 + q5;
#pragma unroll
  for (int reg = 0; reg < 16; ++reg) {
    const int qq = (reg & 3) + 8 * (reg >> 2) + 4 * hi;   // C/D row mapping (m74/m101)
    const float rv = __shfl(rinv, qq);
#pragma unroll
    for (int db = 0; db < 4; ++db)
      O[(size_t)(qgb + qq) * 2048 + db * 32 + colb] = f2bf(oacc[db][reg] * rv);
  }
}

// ---------------- host ----------------
extern "C" void kernel_launch(void* const* d_in, const int* in_sizes, int n_in,
                              void* d_out, int out_size, void* d_ws, size_t ws_size,
                              hipStream_t stream) {
  const float* X  = (const float*)d_in[0];
  const float* Wq = (const float*)d_in[1];
  const float* Wk = (const float*)d_in[2];
  const float* Wv = (const float*)d_in[3];
  const float* Wo = (const float*)d_in[4];
  float* out = (float*)d_out;
  char* ws = (char*)d_ws;
  const size_t MB = 1u << 20;
  u16* Xb    = (u16*)(ws + 0 * MB);
  u16* QKVb  = (u16*)(ws + 16 * MB);
  u16* Wqkvb = (u16*)(ws + 64 * MB);
  u16* Wob   = (u16*)(ws + 96 * MB);
  u16* Kblk  = Xb;
  u16* Vblk  = (u16*)(ws + 64 * MB);
  u16* Ob    = (u16*)(ws + 80 * MB);

  castk<<<8192, 256, 0, stream>>>(X,  Xb, 2097152);
  castk<<<4096, 256, 0, stream>>>(Wq, Wqkvb, 1048576);
  castk<<<4096, 256, 0, stream>>>(Wk, Wqkvb + 4194304, 1048576);
  castk<<<4096, 256, 0, stream>>>(Wv, Wqkvb + 8388608, 1048576);
  castk<<<4096, 256, 0, stream>>>(Wo, Wob, 1048576);

  gemm256<<<384, 512, 0, stream>>>(Xb, Wqkvb, QKVb, 4096, 6144, 2048, 0, 24);

  rope_q<<<4096, 256, 0, stream>>>(QKVb);
  rope_k<<<4096, 256, 0, stream>>>(QKVb, Kblk);
  transpose_v<<<dim3(32, 32), 256, 0, stream>>>(QKVb, Vblk);

  flash3<<<512, 256, 0, stream>>>(QKVb, Kblk, Vblk, Ob);

  gemm256<<<128, 512, 0, stream>>>(Ob, Wob, out, 4096, 2048, 2048, 1, 8);
}